// Round 6
// baseline (438.451 us; speedup 1.0000x reference)
//
#include <hip/hip_runtime.h>
#include <stdint.h>

#define DD 1024
#define MROWS 32768
#define NTK 16   // K-steps: 1024 / 64

typedef __attribute__((ext_vector_type(8))) short short8;
typedef __attribute__((ext_vector_type(8))) unsigned short ushort8;
typedef __attribute__((ext_vector_type(4))) float f32x4;

static __device__ __forceinline__ unsigned short f2bf(float f) {
    union { float f; uint32_t u; } c;
    c.f = f;
    uint32_t u = c.u;
    u += 0x7FFFu + ((u >> 16) & 1u);   // RNE
    return (unsigned short)(u >> 16);
}

static __device__ __forceinline__ void gload_lds16(const void* g, void* l) {
    __builtin_amdgcn_global_load_lds(
        (const __attribute__((address_space(1))) uint32_t*)g,
        (__attribute__((address_space(3))) uint32_t*)l,
        16, 0, 0);
}

#define SBAR() __builtin_amdgcn_s_barrier()
#define SFENCE() __builtin_amdgcn_sched_barrier(0)

static __device__ __forceinline__ short8 cvt8pk(f32x4 lo, f32x4 hi) {
    union { short8 s; uint32_t u[4]; } r;
    asm("v_cvt_pk_bf16_f32 %0, %1, %2" : "=v"(r.u[0]) : "v"(lo[0]), "v"(lo[1]));
    asm("v_cvt_pk_bf16_f32 %0, %1, %2" : "=v"(r.u[1]) : "v"(lo[2]), "v"(lo[3]));
    asm("v_cvt_pk_bf16_f32 %0, %1, %2" : "=v"(r.u[2]) : "v"(hi[0]), "v"(hi[1]));
    asm("v_cvt_pk_bf16_f32 %0, %1, %2" : "=v"(r.u[3]) : "v"(hi[2]), "v"(hi[3]));
    return r.s;
}

// ---------------- weight reconstruction: wT[n][k] = bf16(th*sign*(th>0))[k][n]
__global__ __launch_bounds__(256) void build_wT_kernel(
        const float* __restrict__ th1, const float* __restrict__ sg1,
        const float* __restrict__ th2, const float* __restrict__ sg2,
        unsigned short* __restrict__ wT1, unsigned short* __restrict__ wT2) {
    __shared__ unsigned short tile[64][65];
    const float* th = blockIdx.z ? th2 : th1;
    const float* sg = blockIdx.z ? sg2 : sg1;
    unsigned short* wT = blockIdx.z ? wT2 : wT1;
    const int bk = blockIdx.x, bn = blockIdx.y, t = threadIdx.x;
    #pragma unroll
    for (int i = 0; i < 4; ++i) {
        int idx = i * 256 + t;
        int r = idx >> 4, cg = idx & 15;
        size_t base = (size_t)(bk * 64 + r) * DD + bn * 64 + cg * 4;
        const float4 tv = *(const float4*)&th[base];
        const float4 sv = *(const float4*)&sg[base];
        tile[r][cg * 4 + 0] = f2bf(tv.x > 0.f ? tv.x * sv.x : 0.f);
        tile[r][cg * 4 + 1] = f2bf(tv.y > 0.f ? tv.y * sv.y : 0.f);
        tile[r][cg * 4 + 2] = f2bf(tv.z > 0.f ? tv.z * sv.z : 0.f);
        tile[r][cg * 4 + 3] = f2bf(tv.w > 0.f ? tv.w * sv.w : 0.f);
    }
    __syncthreads();
    #pragma unroll
    for (int i = 0; i < 4; ++i) {
        int idx = i * 256 + t;
        int nr = idx >> 4, kg = idx & 15;
        uint32_t lo = tile[kg * 4 + 0][nr] | ((uint32_t)tile[kg * 4 + 1][nr] << 16);
        uint32_t hi = tile[kg * 4 + 2][nr] | ((uint32_t)tile[kg * 4 + 3][nr] << 16);
        *(uint2*)&wT[(size_t)(bn * 64 + nr) * DD + bk * 64 + kg * 4] = make_uint2(lo, hi);
    }
}

// ---------------- GEMM with A-from-global (no A in LDS), B LDS-dbuf, BK=64.
// 128x128 tile, 4 waves (64x64 each). C = relu(A . Bt^T).
// A_FP32: A fp32 (x), frags cvt_pk'd in regs, store bf16 (Y1).
// else  : A bf16 (Y1), store fp32 (out).
template<bool A_FP32>
__global__ __launch_bounds__(256, 3) void gemm_ag(
        const void* __restrict__ Ap,
        const unsigned short* __restrict__ Bt,   // [1024 n][1024 k] bf16
        void* __restrict__ Cp) {
    __shared__ unsigned short sB[2][128 * 64];   // 16 KiB x2, st-swizzled rows of 128B

    const int tid = threadIdx.x;
    const int lane = tid & 63, wid = tid >> 6;
    const int wm = wid >> 1, wn = wid & 1;
    const int fr = lane & 15, fq = lane >> 4;

    // T1: XCD-chunked bn-minor swizzle (2048 blocks = 256 bm x 8 bn)
    const int s = blockIdx.x;
    const int L = ((s & 7) << 8) + (s >> 3);
    const int bm = L >> 3;
    const int bn = L & 7;

    // B staging: linear LDS dest rows, pre-swizzled global 16B slot
    const unsigned short* bsrc =
        Bt + (size_t)(bn * 128 + wid * 32 + (lane >> 3)) * DD
           + ((lane & 7) ^ ((lane >> 3) & 7)) * 8;
    auto stageB = [&](int p, int kt) {
        #pragma unroll
        for (int j = 0; j < 4; ++j)
            gload_lds16(bsrc + (size_t)j * 8 * DD + kt * 64,
                        &sB[p][(wid * 32 + j * 8) * 64]);
    };

    // A sources (global; row = bm*128 + wm*64 + mi*16 + fr)
    const unsigned short* aB = nullptr;
    const float* aF = nullptr;
    if constexpr (A_FP32) aF = (const float*)Ap + (size_t)(bm * 128 + wm * 64 + fr) * DD;
    else                  aB = (const unsigned short*)Ap + (size_t)(bm * 128 + wm * 64 + fr) * DD;

    const f32x4 vz = {0.f, 0.f, 0.f, 0.f};
    f32x4 acc[4][4];
    #pragma unroll
    for (int i = 0; i < 4; ++i)
        #pragma unroll
        for (int j = 0; j < 4; ++j) acc[i][j] = vz;

    stageB(0, 0);   // prologue

    #pragma unroll 1
    for (int t = 0; t < NTK; ++t) {
        const int p = t & 1;

        // ---- A fragments for this K-step, straight from global ----
        short8 av[4][2];
        #pragma unroll
        for (int mi = 0; mi < 4; ++mi)
            #pragma unroll
            for (int kk = 0; kk < 2; ++kk) {
                if constexpr (A_FP32) {
                    const float* pA = aF + (size_t)mi * 16 * DD + t * 64 + kk * 32 + fq * 8;
                    f32x4 lo = *(const f32x4*)pA;
                    f32x4 hi = *(const f32x4*)(pA + 4);
                    av[mi][kk] = cvt8pk(lo, hi);
                } else {
                    av[mi][kk] = *(const short8*)(aB + (size_t)mi * 16 * DD + t * 64 + kk * 32 + fq * 8);
                }
            }

        // ---- prefetch next B tile; counted wait for current B ----
        if (t + 1 < NTK) {
            stageB(p ^ 1, t + 1);
            if constexpr (A_FP32) asm volatile("s_waitcnt vmcnt(20)" ::: "memory");
            else                  asm volatile("s_waitcnt vmcnt(12)" ::: "memory");
        } else {
            if constexpr (A_FP32) asm volatile("s_waitcnt vmcnt(16)" ::: "memory");
            else                  asm volatile("s_waitcnt vmcnt(8)" ::: "memory");
        }
        SBAR();      // B(t) visible to all waves
        SFENCE();

        // ---- B fragments (swizzled ds_read_b128) + 32 MFMA ----
        short8 bv[4][2];
        #pragma unroll
        for (int ni = 0; ni < 4; ++ni)
            #pragma unroll
            for (int kk = 0; kk < 2; ++kk) {
                int row = wn * 64 + ni * 16 + fr;
                bv[ni][kk] = *(const short8*)((const char*)&sB[p][0]
                               + row * 128 + (((kk * 4 + fq) ^ (row & 7)) << 4));
            }
        __builtin_amdgcn_s_setprio(1);
        #pragma unroll
        for (int mi = 0; mi < 4; ++mi)
            #pragma unroll
            for (int ni = 0; ni < 4; ++ni)
                #pragma unroll
                for (int kk = 0; kk < 2; ++kk)
                    acc[mi][ni] = __builtin_amdgcn_mfma_f32_16x16x32_bf16(
                        av[mi][kk], bv[ni][kk], acc[mi][ni], 0, 0, 0);
        __builtin_amdgcn_s_setprio(0);
        SFENCE();
        SBAR();      // close reads of sB[p] before it is restaged
    }

    // ---- epilogue: ReLU + store ----
    const int orow0 = bm * 128 + wm * 64 + fq * 4;
    const int ocol0 = bn * 128 + wn * 64 + fr;
    #pragma unroll
    for (int mi = 0; mi < 4; ++mi)
        #pragma unroll
        for (int ni = 0; ni < 4; ++ni)
            #pragma unroll
            for (int r = 0; r < 4; ++r) {
                float v = fmaxf(acc[mi][ni][r], 0.f);
                size_t off = (size_t)(orow0 + mi * 16 + r) * DD + (ocol0 + ni * 16);
                if (A_FP32) ((unsigned short*)Cp)[off] = f2bf(v);
                else        ((float*)Cp)[off] = v;
            }
}

// ---------------- fallback (tiny workspace): fused fp32 VALU path
__global__ __launch_bounds__(256) void fallback_fused(
        const float* __restrict__ x,
        const float* __restrict__ th1, const float* __restrict__ sg1,
        const float* __restrict__ th2, const float* __restrict__ sg2,
        float* __restrict__ out) {
    __shared__ float xr[8][DD];
    __shared__ float y1[8][DD];
    const int rb = blockIdx.x * 8;
    const int t = threadIdx.x;
    for (int r = 0; r < 8; ++r)
        for (int i = t; i < DD; i += 256)
            xr[r][i] = x[(size_t)(rb + r) * DD + i];
    __syncthreads();
    for (int jo = 0; jo < 4; ++jo) {
        const int j = jo * 256 + t;
        float a[8] = {0, 0, 0, 0, 0, 0, 0, 0};
        for (int k = 0; k < DD; ++k) {
            float tv = th1[(size_t)k * DD + j];
            float w = tv > 0.f ? tv * sg1[(size_t)k * DD + j] : 0.f;
            #pragma unroll
            for (int r = 0; r < 8; ++r) a[r] += xr[r][k] * w;
        }
        #pragma unroll
        for (int r = 0; r < 8; ++r) y1[r][j] = fmaxf(a[r], 0.f);
    }
    __syncthreads();
    for (int jo = 0; jo < 4; ++jo) {
        const int j = jo * 256 + t;
        float a[8] = {0, 0, 0, 0, 0, 0, 0, 0};
        for (int k = 0; k < DD; ++k) {
            float tv = th2[(size_t)k * DD + j];
            float w = tv > 0.f ? tv * sg2[(size_t)k * DD + j] : 0.f;
            #pragma unroll
            for (int r = 0; r < 8; ++r) a[r] += y1[r][k] * w;
        }
        #pragma unroll
        for (int r = 0; r < 8; ++r) out[(size_t)(rb + r) * DD + j] = fmaxf(a[r], 0.f);
    }
}

extern "C" void kernel_launch(void* const* d_in, const int* in_sizes, int n_in,
                              void* d_out, int out_size, void* d_ws, size_t ws_size,
                              hipStream_t stream) {
    const float* x   = (const float*)d_in[0];
    const float* th1 = (const float*)d_in[1];
    const float* sg1 = (const float*)d_in[2];
    const float* th2 = (const float*)d_in[3];
    const float* sg2 = (const float*)d_in[4];
    float* out = (float*)d_out;

    const size_t need = ((size_t)2 * 1024 * 1024 + (size_t)MROWS * 1024) * 2;  // wT1+wT2+Y1 bf16
    if (ws_size >= need) {
        unsigned short* wT1 = (unsigned short*)d_ws;
        unsigned short* wT2 = wT1 + 1024 * 1024;
        unsigned short* Y1  = wT2 + 1024 * 1024;
        build_wT_kernel<<<dim3(16, 16, 2), 256, 0, stream>>>(th1, sg1, th2, sg2, wT1, wT2);
        gemm_ag<true ><<<dim3((MROWS / 128) * 8), 256, 0, stream>>>(x,  wT1, Y1);
        gemm_ag<false><<<dim3((MROWS / 128) * 8), 256, 0, stream>>>(Y1, wT2, out);
    } else {
        fallback_fused<<<MROWS / 8, 256, 0, stream>>>(x, th1, sg1, th2, sg2, out);
    }
}

// Round 8
// 300.286 us; speedup vs baseline: 1.4601x; 1.4601x over previous
//
#include <hip/hip_runtime.h>
#include <stdint.h>

#define DD 1024
#define MROWS 32768
#define NTK 16   // K-steps: 1024 / 64

typedef __attribute__((ext_vector_type(8))) short short8;
typedef __attribute__((ext_vector_type(8))) unsigned short ushort8;
typedef __attribute__((ext_vector_type(4))) float f32x4;

static __device__ __forceinline__ unsigned short f2bf(float f) {
    union { float f; uint32_t u; } c;
    c.f = f;
    uint32_t u = c.u;
    u += 0x7FFFu + ((u >> 16) & 1u);   // RNE
    return (unsigned short)(u >> 16);
}

static __device__ __forceinline__ void gload_lds16(const void* g, void* l) {
    __builtin_amdgcn_global_load_lds(
        (const __attribute__((address_space(1))) uint32_t*)g,
        (__attribute__((address_space(3))) uint32_t*)l,
        16, 0, 0);
}

#define SBAR() __builtin_amdgcn_s_barrier()
#define SFENCE() __builtin_amdgcn_sched_barrier(0)

static __device__ __forceinline__ ushort8 cvt8pk(f32x4 lo, f32x4 hi) {
    union { ushort8 s; uint32_t u[4]; } r;
    asm("v_cvt_pk_bf16_f32 %0, %1, %2" : "=v"(r.u[0]) : "v"(lo[0]), "v"(lo[1]));
    asm("v_cvt_pk_bf16_f32 %0, %1, %2" : "=v"(r.u[1]) : "v"(lo[2]), "v"(lo[3]));
    asm("v_cvt_pk_bf16_f32 %0, %1, %2" : "=v"(r.u[2]) : "v"(hi[0]), "v"(hi[1]));
    asm("v_cvt_pk_bf16_f32 %0, %1, %2" : "=v"(r.u[3]) : "v"(hi[2]), "v"(hi[3]));
    return r.s;
}

// ---------------- weight reconstruction: wT[n][k] = bf16(th*sign*(th>0))[k][n]
__global__ __launch_bounds__(256) void build_wT_kernel(
        const float* __restrict__ th1, const float* __restrict__ sg1,
        const float* __restrict__ th2, const float* __restrict__ sg2,
        unsigned short* __restrict__ wT1, unsigned short* __restrict__ wT2) {
    __shared__ unsigned short tile[64][65];
    const float* th = blockIdx.z ? th2 : th1;
    const float* sg = blockIdx.z ? sg2 : sg1;
    unsigned short* wT = blockIdx.z ? wT2 : wT1;
    const int bk = blockIdx.x, bn = blockIdx.y, t = threadIdx.x;
    #pragma unroll
    for (int i = 0; i < 4; ++i) {
        int idx = i * 256 + t;
        int r = idx >> 4, cg = idx & 15;
        size_t base = (size_t)(bk * 64 + r) * DD + bn * 64 + cg * 4;
        const float4 tv = *(const float4*)&th[base];
        const float4 sv = *(const float4*)&sg[base];
        tile[r][cg * 4 + 0] = f2bf(tv.x > 0.f ? tv.x * sv.x : 0.f);
        tile[r][cg * 4 + 1] = f2bf(tv.y > 0.f ? tv.y * sv.y : 0.f);
        tile[r][cg * 4 + 2] = f2bf(tv.z > 0.f ? tv.z * sv.z : 0.f);
        tile[r][cg * 4 + 3] = f2bf(tv.w > 0.f ? tv.w * sv.w : 0.f);
    }
    __syncthreads();
    #pragma unroll
    for (int i = 0; i < 4; ++i) {
        int idx = i * 256 + t;
        int nr = idx >> 4, kg = idx & 15;
        uint32_t lo = tile[kg * 4 + 0][nr] | ((uint32_t)tile[kg * 4 + 1][nr] << 16);
        uint32_t hi = tile[kg * 4 + 2][nr] | ((uint32_t)tile[kg * 4 + 3][nr] << 16);
        *(uint2*)&wT[(size_t)(bn * 64 + nr) * DD + bk * 64 + kg * 4] = make_uint2(lo, hi);
    }
}

// ---------------- dbuf 128x128 GEMM, BK=64, conflict-free swizzle, 2 blocks/CU.
// C = relu(A . Bt^T).
// A_FP32: A fp32 (x) reg-staged (cvt_pk -> swizzled ds_write), store bf16 (Y1).
// else  : A bf16 (Y1) via global_load_lds, store fp32 (out).
template<bool A_FP32>
__global__ __launch_bounds__(256, 2) void gemm_v8(
        const void* __restrict__ Ap,
        const unsigned short* __restrict__ Bt,   // [1024 n][1024 k] bf16
        void* __restrict__ Cp) {
    __shared__ unsigned short sA[2][128 * 64];   // 16 KiB x2
    __shared__ unsigned short sB[2][128 * 64];   // 16 KiB x2

    const int tid = threadIdx.x;
    const int lane = tid & 63, wid = tid >> 6;
    const int wm = wid >> 1, wn = wid & 1;
    const int fr = lane & 15, fq = lane >> 4;

    // T1: XCD-chunked bn-minor swizzle (2048 blocks = 256 bm x 8 bn)
    const int s = blockIdx.x;
    const int L = ((s & 7) << 8) + (s >> 3);
    const int bm = L >> 3;
    const int bn = L & 7;

    // staging: linear LDS dest rows, pre-swizzled global 16B slot (involution)
    const unsigned short* bsrc =
        Bt + (size_t)(bn * 128 + wid * 32 + (lane >> 3)) * DD
           + ((lane & 7) ^ ((lane >> 3) & 7)) * 8;
    auto stageB = [&](int p, int kt) {
        #pragma unroll
        for (int j = 0; j < 4; ++j)
            gload_lds16(bsrc + (size_t)j * 8 * DD + kt * 64,
                        &sB[p][(wid * 32 + j * 8) * 64]);
    };

    const unsigned short* ahsrc = nullptr;
    const float* afsrc = nullptr;
    if constexpr (A_FP32) {
        // full-tile coverage: row = tid>>1 (0..127), 32-col half = (tid&1)*32
        afsrc = (const float*)Ap + (size_t)(bm * 128 + (tid >> 1)) * DD + (tid & 1) * 32;
    } else {
        ahsrc = (const unsigned short*)Ap
              + (size_t)(bm * 128 + wid * 32 + (lane >> 3)) * DD
              + ((lane & 7) ^ ((lane >> 3) & 7)) * 8;
    }
    auto stageA = [&](int p, int kt) {   // bf16 path only
        #pragma unroll
        for (int j = 0; j < 4; ++j)
            gload_lds16(ahsrc + (size_t)j * 8 * DD + kt * 64,
                        &sA[p][(wid * 32 + j * 8) * 64]);
    };
    auto ldA = [&](f32x4 (&R)[8], int kt) {  // fp32 path: 32 floats/thread
        #pragma unroll
        for (int j = 0; j < 8; ++j)
            R[j] = *(const f32x4*)(afsrc + kt * 64 + j * 4);
    };
    auto wrA = [&](int p, f32x4 (&R)[8]) {
        const int row = tid >> 1;
        const int s0 = (tid & 1) * 4;        // 4 16B-slots per thread
        char* base = (char*)&sA[p][0] + row * 128;
        *(ushort8*)(base + (((s0 + 0) ^ (row & 7)) << 4)) = cvt8pk(R[0], R[1]);
        *(ushort8*)(base + (((s0 + 1) ^ (row & 7)) << 4)) = cvt8pk(R[2], R[3]);
        *(ushort8*)(base + (((s0 + 2) ^ (row & 7)) << 4)) = cvt8pk(R[4], R[5]);
        *(ushort8*)(base + (((s0 + 3) ^ (row & 7)) << 4)) = cvt8pk(R[6], R[7]);
    };

    const f32x4 vz = {0.f, 0.f, 0.f, 0.f};
    f32x4 acc[4][4];
    #pragma unroll
    for (int i = 0; i < 4; ++i)
        #pragma unroll
        for (int j = 0; j < 4; ++j) acc[i][j] = vz;

    // -------- prologue: tile 0 --------
    if constexpr (A_FP32) {
        f32x4 R0[8];
        ldA(R0, 0);
        stageB(0, 0);
        wrA(0, R0);                                   // compiler waits A-reg loads
        asm volatile("s_waitcnt lgkmcnt(0)" ::: "memory");
    } else {
        stageA(0, 0);
        stageB(0, 0);
    }

    #pragma unroll 1
    for (int t = 0; t < NTK; ++t) {
        const int p = t & 1;
        f32x4 R[8];
        if (t + 1 < NTK) {
            if constexpr (A_FP32) {
                ldA(R, t + 1); stageB(p ^ 1, t + 1);
                // drain prev tile's 4 stageB; keep this iter's 12 ops in flight
                asm volatile("s_waitcnt vmcnt(12)" ::: "memory");
            } else {
                stageA(p ^ 1, t + 1); stageB(p ^ 1, t + 1);
                asm volatile("s_waitcnt vmcnt(8)" ::: "memory");
            }
        } else {
            asm volatile("s_waitcnt vmcnt(0)" ::: "memory");
        }
        SBAR();      // tile t visible to all waves
        SFENCE();

        // ---- fragments (conflict-free swizzled ds_read_b128) ----
        short8 av[4][2], bv[4][2];
        #pragma unroll
        for (int mi = 0; mi < 4; ++mi)
            #pragma unroll
            for (int kk = 0; kk < 2; ++kk) {
                int row = wm * 64 + mi * 16 + fr;
                av[mi][kk] = *(const short8*)((const char*)&sA[p][0]
                               + row * 128 + (((kk * 4 + fq) ^ (row & 7)) << 4));
            }
        #pragma unroll
        for (int ni = 0; ni < 4; ++ni)
            #pragma unroll
            for (int kk = 0; kk < 2; ++kk) {
                int row = wn * 64 + ni * 16 + fr;
                bv[ni][kk] = *(const short8*)((const char*)&sB[p][0]
                               + row * 128 + (((kk * 4 + fq) ^ (row & 7)) << 4));
            }

        __builtin_amdgcn_s_setprio(1);
        #pragma unroll
        for (int mi = 0; mi < 4; ++mi)
            #pragma unroll
            for (int ni = 0; ni < 4; ++ni)
                #pragma unroll
                for (int kk = 0; kk < 2; ++kk)
                    acc[mi][ni] = __builtin_amdgcn_mfma_f32_16x16x32_bf16(
                        av[mi][kk], bv[ni][kk], acc[mi][ni], 0, 0, 0);
        __builtin_amdgcn_s_setprio(0);
        SFENCE();

        if constexpr (A_FP32) {
            if (t + 1 < NTK) {
                wrA(p ^ 1, R);                        // compiler waits R's loads
                asm volatile("s_waitcnt lgkmcnt(0)" ::: "memory");
            }
        }
        SBAR();      // close reads of buffers p before they are restaged
    }

    // -------- epilogue: ReLU + store --------
    const int orow0 = bm * 128 + wm * 64 + fq * 4;
    const int ocol0 = bn * 128 + wn * 64 + fr;
    #pragma unroll
    for (int mi = 0; mi < 4; ++mi)
        #pragma unroll
        for (int ni = 0; ni < 4; ++ni)
            #pragma unroll
            for (int r = 0; r < 4; ++r) {
                float v = fmaxf(acc[mi][ni][r], 0.f);
                size_t off = (size_t)(orow0 + mi * 16 + r) * DD + (ocol0 + ni * 16);
                if (A_FP32) ((unsigned short*)Cp)[off] = f2bf(v);
                else        ((float*)Cp)[off] = v;
            }
}

// ---------------- fallback (tiny workspace): fused fp32 VALU path
__global__ __launch_bounds__(256) void fallback_fused(
        const float* __restrict__ x,
        const float* __restrict__ th1, const float* __restrict__ sg1,
        const float* __restrict__ th2, const float* __restrict__ sg2,
        float* __restrict__ out) {
    __shared__ float xr[8][DD];
    __shared__ float y1[8][DD];
    const int rb = blockIdx.x * 8;
    const int t = threadIdx.x;
    for (int r = 0; r < 8; ++r)
        for (int i = t; i < DD; i += 256)
            xr[r][i] = x[(size_t)(rb + r) * DD + i];
    __syncthreads();
    for (int jo = 0; jo < 4; ++jo) {
        const int j = jo * 256 + t;
        float a[8] = {0, 0, 0, 0, 0, 0, 0, 0};
        for (int k = 0; k < DD; ++k) {
            float tv = th1[(size_t)k * DD + j];
            float w = tv > 0.f ? tv * sg1[(size_t)k * DD + j] : 0.f;
            #pragma unroll
            for (int r = 0; r < 8; ++r) a[r] += xr[r][k] * w;
        }
        #pragma unroll
        for (int r = 0; r < 8; ++r) y1[r][j] = fmaxf(a[r], 0.f);
    }
    __syncthreads();
    for (int jo = 0; jo < 4; ++jo) {
        const int j = jo * 256 + t;
        float a[8] = {0, 0, 0, 0, 0, 0, 0, 0};
        for (int k = 0; k < DD; ++k) {
            float tv = th2[(size_t)k * DD + j];
            float w = tv > 0.f ? tv * sg2[(size_t)k * DD + j] : 0.f;
            #pragma unroll
            for (int r = 0; r < 8; ++r) a[r] += y1[r][k] * w;
        }
        #pragma unroll
        for (int r = 0; r < 8; ++r) out[(size_t)(rb + r) * DD + j] = fmaxf(a[r], 0.f);
    }
}

extern "C" void kernel_launch(void* const* d_in, const int* in_sizes, int n_in,
                              void* d_out, int out_size, void* d_ws, size_t ws_size,
                              hipStream_t stream) {
    const float* x   = (const float*)d_in[0];
    const float* th1 = (const float*)d_in[1];
    const float* sg1 = (const float*)d_in[2];
    const float* th2 = (const float*)d_in[3];
    const float* sg2 = (const float*)d_in[4];
    float* out = (float*)d_out;

    const size_t need = ((size_t)2 * 1024 * 1024 + (size_t)MROWS * 1024) * 2;  // wT1+wT2+Y1 bf16
    if (ws_size >= need) {
        unsigned short* wT1 = (unsigned short*)d_ws;
        unsigned short* wT2 = wT1 + 1024 * 1024;
        unsigned short* Y1  = wT2 + 1024 * 1024;
        build_wT_kernel<<<dim3(16, 16, 2), 256, 0, stream>>>(th1, sg1, th2, sg2, wT1, wT2);
        gemm_v8<true ><<<dim3((MROWS / 128) * 8), 256, 0, stream>>>(x,  wT1, Y1);
        gemm_v8<false><<<dim3((MROWS / 128) * 8), 256, 0, stream>>>(Y1, wT2, out);
    } else {
        fallback_fused<<<MROWS / 8, 256, 0, stream>>>(x, th1, sg1, th2, sg2, out);
    }
}

// Round 9
// 286.668 us; speedup vs baseline: 1.5295x; 1.0475x over previous
//
#include <hip/hip_runtime.h>
#include <stdint.h>

#define DD 1024
#define MROWS 32768
#define NTK 16   // K-steps: 1024 / 64

typedef __attribute__((ext_vector_type(8))) short short8;
typedef __attribute__((ext_vector_type(8))) unsigned short ushort8;
typedef __attribute__((ext_vector_type(4))) float f32x4;

static __device__ __forceinline__ unsigned short f2bf(float f) {
    union { float f; uint32_t u; } c;
    c.f = f;
    uint32_t u = c.u;
    u += 0x7FFFu + ((u >> 16) & 1u);   // RNE
    return (unsigned short)(u >> 16);
}

static __device__ __forceinline__ void gload_lds16(const void* g, void* l) {
    __builtin_amdgcn_global_load_lds(
        (const __attribute__((address_space(1))) uint32_t*)g,
        (__attribute__((address_space(3))) uint32_t*)l,
        16, 0, 0);
}

#define SBAR() __builtin_amdgcn_s_barrier()
#define SFENCE() __builtin_amdgcn_sched_barrier(0)

static __device__ __forceinline__ ushort8 cvt8pk(f32x4 lo, f32x4 hi) {
    union { ushort8 s; uint32_t u[4]; } r;
    asm("v_cvt_pk_bf16_f32 %0, %1, %2" : "=v"(r.u[0]) : "v"(lo[0]), "v"(lo[1]));
    asm("v_cvt_pk_bf16_f32 %0, %1, %2" : "=v"(r.u[1]) : "v"(lo[2]), "v"(lo[3]));
    asm("v_cvt_pk_bf16_f32 %0, %1, %2" : "=v"(r.u[2]) : "v"(hi[0]), "v"(hi[1]));
    asm("v_cvt_pk_bf16_f32 %0, %1, %2" : "=v"(r.u[3]) : "v"(hi[2]), "v"(hi[3]));
    return r.s;
}

// ---------------- weight reconstruction: wT[n][k] = bf16(th*sign*(th>0))[k][n]
__global__ __launch_bounds__(256) void build_wT_kernel(
        const float* __restrict__ th1, const float* __restrict__ sg1,
        const float* __restrict__ th2, const float* __restrict__ sg2,
        unsigned short* __restrict__ wT1, unsigned short* __restrict__ wT2) {
    __shared__ unsigned short tile[64][65];
    const float* th = blockIdx.z ? th2 : th1;
    const float* sg = blockIdx.z ? sg2 : sg1;
    unsigned short* wT = blockIdx.z ? wT2 : wT1;
    const int bk = blockIdx.x, bn = blockIdx.y, t = threadIdx.x;
    #pragma unroll
    for (int i = 0; i < 4; ++i) {
        int idx = i * 256 + t;
        int r = idx >> 4, cg = idx & 15;
        size_t base = (size_t)(bk * 64 + r) * DD + bn * 64 + cg * 4;
        const float4 tv = *(const float4*)&th[base];
        const float4 sv = *(const float4*)&sg[base];
        tile[r][cg * 4 + 0] = f2bf(tv.x > 0.f ? tv.x * sv.x : 0.f);
        tile[r][cg * 4 + 1] = f2bf(tv.y > 0.f ? tv.y * sv.y : 0.f);
        tile[r][cg * 4 + 2] = f2bf(tv.z > 0.f ? tv.z * sv.z : 0.f);
        tile[r][cg * 4 + 3] = f2bf(tv.w > 0.f ? tv.w * sv.w : 0.f);
    }
    __syncthreads();
    #pragma unroll
    for (int i = 0; i < 4; ++i) {
        int idx = i * 256 + t;
        int nr = idx >> 4, kg = idx & 15;
        uint32_t lo = tile[kg * 4 + 0][nr] | ((uint32_t)tile[kg * 4 + 1][nr] << 16);
        uint32_t hi = tile[kg * 4 + 2][nr] | ((uint32_t)tile[kg * 4 + 3][nr] << 16);
        *(uint2*)&wT[(size_t)(bn * 64 + nr) * DD + bk * 64 + kg * 4] = make_uint2(lo, hi);
    }
}

// ---------------- 128x128 GEMM, BK=64; A triple-buffered (prefetch dist 2),
// B double-buffered (dist 1); ordered VMEM queue + tile-granular counted vmcnt.
// C = relu(A . Bt^T).
// A_FP32: A fp32 (x), 2-iter in-flight reg loads -> cvt_pk -> swizzled ds_write.
// else  : A bf16 (Y1) via global_load_lds (pre-swizzled source).
template<bool A_FP32>
__global__ __launch_bounds__(256, 2) void gemm_v9(
        const void* __restrict__ Ap,
        const unsigned short* __restrict__ Bt,   // [1024 n][1024 k] bf16
        void* __restrict__ Cp) {
    __shared__ unsigned short sA[3][128 * 64];   // 16 KiB x3
    __shared__ unsigned short sB[2][128 * 64];   // 16 KiB x2  (total 80 KiB)

    const int tid = threadIdx.x;
    const int lane = tid & 63, wid = tid >> 6;
    const int wm = wid >> 1, wn = wid & 1;
    const int fr = lane & 15, fq = lane >> 4;

    // T1: XCD-chunked bn-minor swizzle (2048 blocks = 256 bm x 8 bn)
    const int s = blockIdx.x;
    const int L = ((s & 7) << 8) + (s >> 3);
    const int bm = L >> 3;
    const int bn = L & 7;

    // B staging: linear LDS dest, pre-swizzled global 16B slot (involution)
    const unsigned short* bsrc =
        Bt + (size_t)(bn * 128 + wid * 32 + (lane >> 3)) * DD
           + ((lane & 7) ^ ((lane >> 3) & 7)) * 8;
    auto stageB = [&](int p, int kt) {
        #pragma unroll
        for (int j = 0; j < 4; ++j)
            gload_lds16(bsrc + (size_t)j * 8 * DD + kt * 64,
                        &sB[p][(wid * 32 + j * 8) * 64]);
    };

    const unsigned short* ahsrc = nullptr;
    const float* afsrc = nullptr;
    if constexpr (A_FP32) {
        afsrc = (const float*)Ap + (size_t)(bm * 128 + (tid >> 1)) * DD + (tid & 1) * 32;
    } else {
        ahsrc = (const unsigned short*)Ap
              + (size_t)(bm * 128 + wid * 32 + (lane >> 3)) * DD
              + ((lane & 7) ^ ((lane >> 3) & 7)) * 8;
    }
    auto stageA = [&](int p, int kt) {   // bf16 path
        #pragma unroll
        for (int j = 0; j < 4; ++j)
            gload_lds16(ahsrc + (size_t)j * 8 * DD + kt * 64,
                        &sA[p][(wid * 32 + j * 8) * 64]);
    };
    auto ldA = [&](f32x4 (&R)[8], int kt) {  // fp32 path: 32 floats/thread
        #pragma unroll
        for (int j = 0; j < 8; ++j)
            R[j] = *(const f32x4*)(afsrc + kt * 64 + j * 4);
    };
    auto wrA = [&](int p, f32x4 (&R)[8]) {
        const int row = tid >> 1;
        const int s0 = (tid & 1) * 4;        // 4 16B-slots per thread
        char* base = (char*)&sA[p][0] + row * 128;
        *(ushort8*)(base + (((s0 + 0) ^ (row & 7)) << 4)) = cvt8pk(R[0], R[1]);
        *(ushort8*)(base + (((s0 + 1) ^ (row & 7)) << 4)) = cvt8pk(R[2], R[3]);
        *(ushort8*)(base + (((s0 + 2) ^ (row & 7)) << 4)) = cvt8pk(R[4], R[5]);
        *(ushort8*)(base + (((s0 + 3) ^ (row & 7)) << 4)) = cvt8pk(R[6], R[7]);
    };

    const f32x4 vz = {0.f, 0.f, 0.f, 0.f};
    f32x4 acc[4][4];
    #pragma unroll
    for (int i = 0; i < 4; ++i)
        #pragma unroll
        for (int j = 0; j < 4; ++j) acc[i][j] = vz;

    // -------- prologue (queue matches steady-state issue order) --------
    f32x4 Re[8], Ro[8];
    if constexpr (A_FP32) {
        ldA(Re, 0);              // tile 0 -> regs
        stageB(0, 0);            // B(0)
        ldA(Ro, 1);              // tile 1 -> regs (2-iter in flight)
        wrA(0, Re);              // compiler auto-waits ldA(0)
        asm volatile("s_waitcnt lgkmcnt(0)" ::: "memory");
    } else {
        stageA(0, 0);            // A(0)
        stageB(0, 0);            // B(0)
        stageA(1, 1);            // A(1)
    }

    #pragma unroll 1
    for (int t = 0; t < NTK; ++t) {
        const int pa = t % 3, pb = t & 1;

        // ---- top: issue next stages in queue order [B(t+1), A(t+2)] ----
        if (t + 1 < NTK) stageB(pb ^ 1, t + 1);
        if constexpr (A_FP32) {
            if (t + 2 < NTK) { if (t & 1) ldA(Ro, t + 2); else ldA(Re, t + 2); }
            if (t + 2 < NTK)      asm volatile("s_waitcnt vmcnt(20)" ::: "memory");
            else if (t + 1 < NTK) asm volatile("s_waitcnt vmcnt(12)" ::: "memory");
            else                  asm volatile("s_waitcnt vmcnt(0)"  ::: "memory");
        } else {
            if (t + 2 < NTK) stageA((t + 2) % 3, t + 2);
            if (t + 2 < NTK)      asm volatile("s_waitcnt vmcnt(12)" ::: "memory");
            else if (t + 1 < NTK) asm volatile("s_waitcnt vmcnt(8)"  ::: "memory");
            else                  asm volatile("s_waitcnt vmcnt(0)"  ::: "memory");
        }
        SBAR();      // tile t (A and B) visible to all waves
        SFENCE();

        // ---- fragments (conflict-free swizzled ds_read_b128) ----
        short8 av[4][2], bv[4][2];
        #pragma unroll
        for (int mi = 0; mi < 4; ++mi)
            #pragma unroll
            for (int kk = 0; kk < 2; ++kk) {
                int row = wm * 64 + mi * 16 + fr;
                av[mi][kk] = *(const short8*)((const char*)&sA[pa][0]
                               + row * 128 + (((kk * 4 + fq) ^ (row & 7)) << 4));
            }
        #pragma unroll
        for (int ni = 0; ni < 4; ++ni)
            #pragma unroll
            for (int kk = 0; kk < 2; ++kk) {
                int row = wn * 64 + ni * 16 + fr;
                bv[ni][kk] = *(const short8*)((const char*)&sB[pb][0]
                               + row * 128 + (((kk * 4 + fq) ^ (row & 7)) << 4));
            }

        __builtin_amdgcn_s_setprio(1);
        #pragma unroll
        for (int mi = 0; mi < 4; ++mi)
            #pragma unroll
            for (int ni = 0; ni < 4; ++ni)
                #pragma unroll
                for (int kk = 0; kk < 2; ++kk)
                    acc[mi][ni] = __builtin_amdgcn_mfma_f32_16x16x32_bf16(
                        av[mi][kk], bv[ni][kk], acc[mi][ni], 0, 0, 0);
        __builtin_amdgcn_s_setprio(0);
        SFENCE();

        // ---- bottom: fp32 path writes tile t+1 into LDS (regs from iter t-1) ----
        if constexpr (A_FP32) {
            if (t + 1 < NTK) {
                if (t & 1) wrA((t + 1) % 3, Re);   // t odd  -> tile t+1 even -> Re
                else       wrA((t + 1) % 3, Ro);   // t even -> tile t+1 odd  -> Ro
                asm volatile("s_waitcnt lgkmcnt(0)" ::: "memory");
            }
        }
        SBAR();      // close reads of tile t's buffers
    }

    // -------- epilogue: ReLU + store --------
    const int orow0 = bm * 128 + wm * 64 + fq * 4;
    const int ocol0 = bn * 128 + wn * 64 + fr;
    #pragma unroll
    for (int mi = 0; mi < 4; ++mi)
        #pragma unroll
        for (int ni = 0; ni < 4; ++ni)
            #pragma unroll
            for (int r = 0; r < 4; ++r) {
                float v = fmaxf(acc[mi][ni][r], 0.f);
                size_t off = (size_t)(orow0 + mi * 16 + r) * DD + (ocol0 + ni * 16);
                if (A_FP32) ((unsigned short*)Cp)[off] = f2bf(v);
                else        ((float*)Cp)[off] = v;
            }
}

// ---------------- fallback (tiny workspace): fused fp32 VALU path
__global__ __launch_bounds__(256) void fallback_fused(
        const float* __restrict__ x,
        const float* __restrict__ th1, const float* __restrict__ sg1,
        const float* __restrict__ th2, const float* __restrict__ sg2,
        float* __restrict__ out) {
    __shared__ float xr[8][DD];
    __shared__ float y1[8][DD];
    const int rb = blockIdx.x * 8;
    const int t = threadIdx.x;
    for (int r = 0; r < 8; ++r)
        for (int i = t; i < DD; i += 256)
            xr[r][i] = x[(size_t)(rb + r) * DD + i];
    __syncthreads();
    for (int jo = 0; jo < 4; ++jo) {
        const int j = jo * 256 + t;
        float a[8] = {0, 0, 0, 0, 0, 0, 0, 0};
        for (int k = 0; k < DD; ++k) {
            float tv = th1[(size_t)k * DD + j];
            float w = tv > 0.f ? tv * sg1[(size_t)k * DD + j] : 0.f;
            #pragma unroll
            for (int r = 0; r < 8; ++r) a[r] += xr[r][k] * w;
        }
        #pragma unroll
        for (int r = 0; r < 8; ++r) y1[r][j] = fmaxf(a[r], 0.f);
    }
    __syncthreads();
    for (int jo = 0; jo < 4; ++jo) {
        const int j = jo * 256 + t;
        float a[8] = {0, 0, 0, 0, 0, 0, 0, 0};
        for (int k = 0; k < DD; ++k) {
            float tv = th2[(size_t)k * DD + j];
            float w = tv > 0.f ? tv * sg2[(size_t)k * DD + j] : 0.f;
            #pragma unroll
            for (int r = 0; r < 8; ++r) a[r] += y1[r][k] * w;
        }
        #pragma unroll
        for (int r = 0; r < 8; ++r) out[(size_t)(rb + r) * DD + j] = fmaxf(a[r], 0.f);
    }
}

extern "C" void kernel_launch(void* const* d_in, const int* in_sizes, int n_in,
                              void* d_out, int out_size, void* d_ws, size_t ws_size,
                              hipStream_t stream) {
    const float* x   = (const float*)d_in[0];
    const float* th1 = (const float*)d_in[1];
    const float* sg1 = (const float*)d_in[2];
    const float* th2 = (const float*)d_in[3];
    const float* sg2 = (const float*)d_in[4];
    float* out = (float*)d_out;

    const size_t need = ((size_t)2 * 1024 * 1024 + (size_t)MROWS * 1024) * 2;  // wT1+wT2+Y1 bf16
    if (ws_size >= need) {
        unsigned short* wT1 = (unsigned short*)d_ws;
        unsigned short* wT2 = wT1 + 1024 * 1024;
        unsigned short* Y1  = wT2 + 1024 * 1024;
        build_wT_kernel<<<dim3(16, 16, 2), 256, 0, stream>>>(th1, sg1, th2, sg2, wT1, wT2);
        gemm_v9<true ><<<dim3((MROWS / 128) * 8), 256, 0, stream>>>(x,  wT1, Y1);
        gemm_v9<false><<<dim3((MROWS / 128) * 8), 256, 0, stream>>>(Y1, wT2, out);
    } else {
        fallback_fused<<<MROWS / 8, 256, 0, stream>>>(x, th1, sg1, th2, sg2, out);
    }
}

// Round 10
// 241.903 us; speedup vs baseline: 1.8125x; 1.1851x over previous
//
#include <hip/hip_runtime.h>
#include <stdint.h>

#define DD 1024
#define MROWS 32768
#define NTK 16   // K-tiles: 1024 / 64

typedef __attribute__((ext_vector_type(8))) short short8;
typedef __attribute__((ext_vector_type(8))) unsigned short ushort8;
typedef __attribute__((ext_vector_type(4))) float f32x4;

static __device__ __forceinline__ unsigned short f2bf(float f) {
    union { float f; uint32_t u; } c;
    c.f = f;
    uint32_t u = c.u;
    u += 0x7FFFu + ((u >> 16) & 1u);   // RNE
    return (unsigned short)(u >> 16);
}

static __device__ __forceinline__ void gload_lds16(const void* g, void* l) {
    __builtin_amdgcn_global_load_lds(
        (const __attribute__((address_space(1))) uint32_t*)g,
        (__attribute__((address_space(3))) uint32_t*)l,
        16, 0, 0);
}

#define SBAR() __builtin_amdgcn_s_barrier()
#define SFENCE() __builtin_amdgcn_sched_barrier(0)
#define LGKM0() asm volatile("s_waitcnt lgkmcnt(0)" ::: "memory")

static __device__ __forceinline__ ushort8 cvt8pk(f32x4 lo, f32x4 hi) {
    union { ushort8 s; uint32_t u[4]; } r;
    asm("v_cvt_pk_bf16_f32 %0, %1, %2" : "=v"(r.u[0]) : "v"(lo[0]), "v"(lo[1]));
    asm("v_cvt_pk_bf16_f32 %0, %1, %2" : "=v"(r.u[1]) : "v"(lo[2]), "v"(lo[3]));
    asm("v_cvt_pk_bf16_f32 %0, %1, %2" : "=v"(r.u[2]) : "v"(hi[0]), "v"(hi[1]));
    asm("v_cvt_pk_bf16_f32 %0, %1, %2" : "=v"(r.u[3]) : "v"(hi[2]), "v"(hi[3]));
    return r.s;
}

// ---------------- weight reconstruction: wT[n][k] = bf16(th*sign*(th>0))[k][n]
__global__ __launch_bounds__(256) void build_wT_kernel(
        const float* __restrict__ th1, const float* __restrict__ sg1,
        const float* __restrict__ th2, const float* __restrict__ sg2,
        unsigned short* __restrict__ wT1, unsigned short* __restrict__ wT2) {
    __shared__ unsigned short tile[64][65];
    const float* th = blockIdx.z ? th2 : th1;
    const float* sg = blockIdx.z ? sg2 : sg1;
    unsigned short* wT = blockIdx.z ? wT2 : wT1;
    const int bk = blockIdx.x, bn = blockIdx.y, t = threadIdx.x;
    #pragma unroll
    for (int i = 0; i < 4; ++i) {
        int idx = i * 256 + t;
        int r = idx >> 4, cg = idx & 15;
        size_t base = (size_t)(bk * 64 + r) * DD + bn * 64 + cg * 4;
        const float4 tv = *(const float4*)&th[base];
        const float4 sv = *(const float4*)&sg[base];
        tile[r][cg * 4 + 0] = f2bf(tv.x > 0.f ? tv.x * sv.x : 0.f);
        tile[r][cg * 4 + 1] = f2bf(tv.y > 0.f ? tv.y * sv.y : 0.f);
        tile[r][cg * 4 + 2] = f2bf(tv.z > 0.f ? tv.z * sv.z : 0.f);
        tile[r][cg * 4 + 3] = f2bf(tv.w > 0.f ? tv.w * sv.w : 0.f);
    }
    __syncthreads();
    #pragma unroll
    for (int i = 0; i < 4; ++i) {
        int idx = i * 256 + t;
        int nr = idx >> 4, kg = idx & 15;
        uint32_t lo = tile[kg * 4 + 0][nr] | ((uint32_t)tile[kg * 4 + 1][nr] << 16);
        uint32_t hi = tile[kg * 4 + 2][nr] | ((uint32_t)tile[kg * 4 + 3][nr] << 16);
        *(uint2*)&wT[(size_t)(bn * 64 + nr) * DD + bk * 64 + kg * 4] = make_uint2(lo, hi);
    }
}

// ---- helpers for the 8-phase kernel ----
// stage one half-tile (128 rows x 64 bf16) of K-tile u into dstbuf (linear rows)
static __device__ __forceinline__ void stG(unsigned short* dstbuf,
        const unsigned short* src_t, int h, int u, int wid) {
    #pragma unroll
    for (int j = 0; j < 2; ++j) {
        const int r0 = h * 128 + j * 64 + wid * 8;
        gload_lds16(src_t + (size_t)(h * 128 + j * 64) * DD + u * 64, dstbuf + r0 * 64);
    }
}

template<int MB>
static __device__ __forceinline__ void rdA4(short8 (&d)[4][2],
        const unsigned short* buf, int wm, int fr, int fq) {
    #pragma unroll
    for (int mi = 0; mi < 4; ++mi)
        #pragma unroll
        for (int kk = 0; kk < 2; ++kk) {
            int row = wm * 128 + (MB + mi) * 16 + fr;
            d[mi][kk] = *(const short8*)((const char*)buf + row * 128
                          + (((kk * 4 + fq) ^ (row & 7)) << 4));
        }
}
template<int NB>
static __device__ __forceinline__ void rdB2(short8 (&d)[2][2],
        const unsigned short* buf, int wn, int fr, int fq) {
    #pragma unroll
    for (int ni = 0; ni < 2; ++ni)
        #pragma unroll
        for (int kk = 0; kk < 2; ++kk) {
            int row = wn * 64 + (NB + ni) * 16 + fr;
            d[ni][kk] = *(const short8*)((const char*)buf + row * 128
                          + (((kk * 4 + fq) ^ (row & 7)) << 4));
        }
}
template<int MI0, int NI0>
static __device__ __forceinline__ void mfma16(f32x4 (&acc)[8][4],
        const short8 (&af)[4][2], const short8 (&bf)[2][2]) {
    #pragma unroll
    for (int mi = 0; mi < 4; ++mi)
        #pragma unroll
        for (int ni = 0; ni < 2; ++ni)
            #pragma unroll
            for (int kk = 0; kk < 2; ++kk)
                acc[MI0 + mi][NI0 + ni] = __builtin_amdgcn_mfma_f32_16x16x32_bf16(
                    af[mi][kk], bf[ni][kk], acc[MI0 + mi][NI0 + ni], 0, 0, 0);
}
static __device__ __forceinline__ void ldA8(f32x4 (&R)[8], const float* af, int u) {
    #pragma unroll
    for (int j = 0; j < 8; ++j) R[j] = *(const f32x4*)(af + u * 64 + j * 4);
}
static __device__ __forceinline__ void wrA8(unsigned short* dstbuf,
        const f32x4 (&R)[8], int tid) {
    const int row = tid >> 1;
    const int s0 = (tid & 1) * 4;
    char* base = (char*)dstbuf + row * 128;
    #pragma unroll
    for (int i = 0; i < 4; ++i)
        *(ushort8*)(base + (((s0 + i) ^ (row & 7)) << 4)) = cvt8pk(R[2 * i], R[2 * i + 1]);
}

// One K-tile u (4 C-quadrant phases). Buffer C holds A(u),B(u).
// Stage cadence: q0/q1 -> A(u+1) halves into buf C^1 (gemm1: ldA at q0, wrA at q1);
//                q2/q3 -> B(u+2) halves into buf C (B(u) LDS dead after q1).
template<bool A_FP32, int C, bool ST_A, bool ST_B, int WAITN>
static __device__ __forceinline__ void ktile(
        unsigned short (&sA)[2][256 * 64], unsigned short (&sB)[2][256 * 64],
        int u, int tid, int wid, int wm, int wn, int fr, int fq,
        const unsigned short* asrc, const unsigned short* bsrc, const float* afsrc,
        f32x4 (&acc)[8][4]) {
    constexpr int NX = C ^ 1;
    short8 aR[4][2], b01[2][2], b23[2][2];
    f32x4 R[8];
    // ---- q0: 12 ds_reads; C[mi0-3][ni0-1] ----
    rdA4<0>(aR, sA[C], wm, fr, fq);
    rdB2<0>(b01, sB[C], wn, fr, fq);
    if (ST_A) {
        if constexpr (A_FP32) ldA8(R, afsrc, u + 1);
        else stG(sA[NX], asrc, 0, u + 1, wid);
    }
    asm volatile("s_waitcnt lgkmcnt(8)" ::: "memory");
    SBAR(); LGKM0(); SFENCE();
    __builtin_amdgcn_s_setprio(1);
    mfma16<0, 0>(acc, aR, b01);
    __builtin_amdgcn_s_setprio(0);
    SBAR();
    // ---- q1: 4 ds_reads; C[mi0-3][ni2-3] ----
    rdB2<2>(b23, sB[C], wn, fr, fq);
    if (ST_A) {
        if constexpr (A_FP32) wrA8(sA[NX], R, tid);
        else stG(sA[NX], asrc, 1, u + 1, wid);
    }
    SBAR(); LGKM0(); SFENCE();
    __builtin_amdgcn_s_setprio(1);
    mfma16<0, 2>(acc, aR, b23);
    __builtin_amdgcn_s_setprio(0);
    SBAR();
    // ---- q2: 8 ds_reads; C[mi4-7][ni2-3] ----
    rdA4<4>(aR, sA[C], wm, fr, fq);
    if (ST_B) stG(sB[C], bsrc, 0, u + 2, wid);
    SBAR(); LGKM0(); SFENCE();
    __builtin_amdgcn_s_setprio(1);
    mfma16<4, 2>(acc, aR, b23);
    __builtin_amdgcn_s_setprio(0);
    SBAR();
    // ---- q3: 0 ds_reads; C[mi4-7][ni0-1]; counted vmcnt ----
    if (ST_B) stG(sB[C], bsrc, 1, u + 2, wid);
    if constexpr (WAITN == 4) asm volatile("s_waitcnt vmcnt(4)" ::: "memory");
    else if constexpr (WAITN == 0) asm volatile("s_waitcnt vmcnt(0)" ::: "memory");
    SBAR(); SFENCE();
    __builtin_amdgcn_s_setprio(1);
    mfma16<4, 0>(acc, aR, b01);
    __builtin_amdgcn_s_setprio(0);
    SBAR();
}

// ---------------- 256x256 8-phase GEMM: C = relu(A . Bt^T)
// A_FP32: A fp32 (x) reg-staged, stores bf16 (Y1). else: A bf16 (Y1), stores fp32.
template<bool A_FP32>
__global__ __launch_bounds__(512, 2) void gemm_v10(
        const void* __restrict__ Ap,
        const unsigned short* __restrict__ Bt,   // [1024 n][1024 k] bf16
        void* __restrict__ Cp) {
    __shared__ unsigned short sA[2][256 * 64];   // 32 KiB x2
    __shared__ unsigned short sB[2][256 * 64];   // 32 KiB x2 (total 128 KiB)

    const int tid = threadIdx.x;
    const int lane = tid & 63, wid = tid >> 6;
    const int wm = wid >> 2, wn = wid & 3;        // 2M x 4N waves
    const int fr = lane & 15, fq = lane >> 4;

    // T1: XCD-chunked bn-minor swizzle (512 blocks = 128 bm x 4 bn)
    const int s = blockIdx.x;
    const int L = (s & 7) * 64 + (s >> 3);
    const int bm = L >> 2, bn = L & 3;

    // staging bases (pre-swizzled global slot; row add (lane>>3) per-thread)
    const unsigned short* bsrc = Bt + (size_t)(bn * 256 + wid * 8 + (lane >> 3)) * DD
                                    + ((lane & 7) ^ (lane >> 3)) * 8;
    const unsigned short* asrc = nullptr;
    const float* afsrc = nullptr;
    if constexpr (A_FP32)
        afsrc = (const float*)Ap + (size_t)(bm * 256 + (tid >> 1)) * DD + (tid & 1) * 32;
    else
        asrc = (const unsigned short*)Ap + (size_t)(bm * 256 + wid * 8 + (lane >> 3)) * DD
             + ((lane & 7) ^ (lane >> 3)) * 8;

    const f32x4 vz = {0.f, 0.f, 0.f, 0.f};
    f32x4 acc[8][4];
    #pragma unroll
    for (int i = 0; i < 8; ++i)
        #pragma unroll
        for (int j = 0; j < 4; ++j) acc[i][j] = vz;

    // -------- prologue: A(0), B(0), B(1) --------
    if constexpr (A_FP32) {
        f32x4 R0[8];
        ldA8(R0, afsrc, 0);
        stG(sB[0], bsrc, 0, 0, wid); stG(sB[0], bsrc, 1, 0, wid);
        stG(sB[1], bsrc, 0, 1, wid); stG(sB[1], bsrc, 1, 1, wid);
        wrA8(sA[0], R0, tid);                     // compiler drains ldA before writes
        LGKM0();
        asm volatile("s_waitcnt vmcnt(4)" ::: "memory");   // B(0) done, B(1) in flight
    } else {
        stG(sA[0], asrc, 0, 0, wid); stG(sA[0], asrc, 1, 0, wid);
        stG(sB[0], bsrc, 0, 0, wid); stG(sB[0], bsrc, 1, 0, wid);
        stG(sB[1], bsrc, 0, 1, wid); stG(sB[1], bsrc, 1, 1, wid);
        asm volatile("s_waitcnt vmcnt(4)" ::: "memory");   // A(0),B(0) done
    }
    SBAR();

    #pragma unroll 1
    for (int u = 0; u < NTK - 2; u += 2) {
        ktile<A_FP32, 0, true, true, 4>(sA, sB, u,     tid, wid, wm, wn, fr, fq, asrc, bsrc, afsrc, acc);
        ktile<A_FP32, 1, true, true, 4>(sA, sB, u + 1, tid, wid, wm, wn, fr, fq, asrc, bsrc, afsrc, acc);
    }
    ktile<A_FP32, 0, true,  false, 0 >(sA, sB, NTK - 2, tid, wid, wm, wn, fr, fq, asrc, bsrc, afsrc, acc);
    ktile<A_FP32, 1, false, false, -1>(sA, sB, NTK - 1, tid, wid, wm, wn, fr, fq, asrc, bsrc, afsrc, acc);

    // -------- epilogue: ReLU + store --------
    const int orow0 = bm * 256 + wm * 128 + fq * 4;
    const int ocol0 = bn * 256 + wn * 64 + fr;
    #pragma unroll
    for (int mi = 0; mi < 8; ++mi)
        #pragma unroll
        for (int ni = 0; ni < 4; ++ni)
            #pragma unroll
            for (int r = 0; r < 4; ++r) {
                float v = fmaxf(acc[mi][ni][r], 0.f);
                size_t off = (size_t)(orow0 + mi * 16 + r) * DD + (ocol0 + ni * 16);
                if (A_FP32) ((unsigned short*)Cp)[off] = f2bf(v);
                else        ((float*)Cp)[off] = v;
            }
}

// ---------------- fallback (tiny workspace): fused fp32 VALU path
__global__ __launch_bounds__(256) void fallback_fused(
        const float* __restrict__ x,
        const float* __restrict__ th1, const float* __restrict__ sg1,
        const float* __restrict__ th2, const float* __restrict__ sg2,
        float* __restrict__ out) {
    __shared__ float xr[8][DD];
    __shared__ float y1[8][DD];
    const int rb = blockIdx.x * 8;
    const int t = threadIdx.x;
    for (int r = 0; r < 8; ++r)
        for (int i = t; i < DD; i += 256)
            xr[r][i] = x[(size_t)(rb + r) * DD + i];
    __syncthreads();
    for (int jo = 0; jo < 4; ++jo) {
        const int j = jo * 256 + t;
        float a[8] = {0, 0, 0, 0, 0, 0, 0, 0};
        for (int k = 0; k < DD; ++k) {
            float tv = th1[(size_t)k * DD + j];
            float w = tv > 0.f ? tv * sg1[(size_t)k * DD + j] : 0.f;
            #pragma unroll
            for (int r = 0; r < 8; ++r) a[r] += xr[r][k] * w;
        }
        #pragma unroll
        for (int r = 0; r < 8; ++r) y1[r][j] = fmaxf(a[r], 0.f);
    }
    __syncthreads();
    for (int jo = 0; jo < 4; ++jo) {
        const int j = jo * 256 + t;
        float a[8] = {0, 0, 0, 0, 0, 0, 0, 0};
        for (int k = 0; k < DD; ++k) {
            float tv = th2[(size_t)k * DD + j];
            float w = tv > 0.f ? tv * sg2[(size_t)k * DD + j] : 0.f;
            #pragma unroll
            for (int r = 0; r < 8; ++r) a[r] += y1[r][k] * w;
        }
        #pragma unroll
        for (int r = 0; r < 8; ++r) out[(size_t)(rb + r) * DD + j] = fmaxf(a[r], 0.f);
    }
}

extern "C" void kernel_launch(void* const* d_in, const int* in_sizes, int n_in,
                              void* d_out, int out_size, void* d_ws, size_t ws_size,
                              hipStream_t stream) {
    const float* x   = (const float*)d_in[0];
    const float* th1 = (const float*)d_in[1];
    const float* sg1 = (const float*)d_in[2];
    const float* th2 = (const float*)d_in[3];
    const float* sg2 = (const float*)d_in[4];
    float* out = (float*)d_out;

    const size_t need = ((size_t)2 * 1024 * 1024 + (size_t)MROWS * 1024) * 2;  // wT1+wT2+Y1 bf16
    if (ws_size >= need) {
        unsigned short* wT1 = (unsigned short*)d_ws;
        unsigned short* wT2 = wT1 + 1024 * 1024;
        unsigned short* Y1  = wT2 + 1024 * 1024;
        build_wT_kernel<<<dim3(16, 16, 2), 256, 0, stream>>>(th1, sg1, th2, sg2, wT1, wT2);
        gemm_v10<true ><<<dim3((MROWS / 256) * 4), 512, 0, stream>>>(x,  wT1, Y1);
        gemm_v10<false><<<dim3((MROWS / 256) * 4), 512, 0, stream>>>(Y1, wT2, out);
    } else {
        fallback_fused<<<MROWS / 8, 256, 0, stream>>>(x, th1, sg1, th2, sg2, out);
    }
}

// Round 11
// 222.991 us; speedup vs baseline: 1.9662x; 1.0848x over previous
//
#include <hip/hip_runtime.h>
#include <stdint.h>

#define DD 1024
#define MROWS 32768
#define NTK 32   // K-tiles: 1024 / 32

typedef __attribute__((ext_vector_type(8))) short short8;
typedef __attribute__((ext_vector_type(8))) unsigned short ushort8;
typedef __attribute__((ext_vector_type(4))) float f32x4;

static __device__ __forceinline__ unsigned short f2bf(float f) {
    union { float f; uint32_t u; } c;
    c.f = f;
    uint32_t u = c.u;
    u += 0x7FFFu + ((u >> 16) & 1u);   // RNE
    return (unsigned short)(u >> 16);
}

static __device__ __forceinline__ void gload_lds16(const void* g, void* l) {
    __builtin_amdgcn_global_load_lds(
        (const __attribute__((address_space(1))) uint32_t*)g,
        (__attribute__((address_space(3))) uint32_t*)l,
        16, 0, 0);
}

#define SBAR() __builtin_amdgcn_s_barrier()
#define SFENCE() __builtin_amdgcn_sched_barrier(0)
#define LGKM0() asm volatile("s_waitcnt lgkmcnt(0)" ::: "memory")
#define VMC0()  asm volatile("s_waitcnt vmcnt(0)" ::: "memory")

static __device__ __forceinline__ ushort8 cvt8pk(f32x4 lo, f32x4 hi) {
    union { ushort8 s; uint32_t u[4]; } r;
    asm("v_cvt_pk_bf16_f32 %0, %1, %2" : "=v"(r.u[0]) : "v"(lo[0]), "v"(lo[1]));
    asm("v_cvt_pk_bf16_f32 %0, %1, %2" : "=v"(r.u[1]) : "v"(lo[2]), "v"(lo[3]));
    asm("v_cvt_pk_bf16_f32 %0, %1, %2" : "=v"(r.u[2]) : "v"(hi[0]), "v"(hi[1]));
    asm("v_cvt_pk_bf16_f32 %0, %1, %2" : "=v"(r.u[3]) : "v"(hi[2]), "v"(hi[3]));
    return r.s;
}

// ---------------- weight reconstruction: wT[n][k] = bf16(th*sign*(th>0))[k][n]
__global__ __launch_bounds__(256) void build_wT_kernel(
        const float* __restrict__ th1, const float* __restrict__ sg1,
        const float* __restrict__ th2, const float* __restrict__ sg2,
        unsigned short* __restrict__ wT1, unsigned short* __restrict__ wT2) {
    __shared__ unsigned short tile[64][65];
    const float* th = blockIdx.z ? th2 : th1;
    const float* sg = blockIdx.z ? sg2 : sg1;
    unsigned short* wT = blockIdx.z ? wT2 : wT1;
    const int bk = blockIdx.x, bn = blockIdx.y, t = threadIdx.x;
    #pragma unroll
    for (int i = 0; i < 4; ++i) {
        int idx = i * 256 + t;
        int r = idx >> 4, cg = idx & 15;
        size_t base = (size_t)(bk * 64 + r) * DD + bn * 64 + cg * 4;
        const float4 tv = *(const float4*)&th[base];
        const float4 sv = *(const float4*)&sg[base];
        tile[r][cg * 4 + 0] = f2bf(tv.x > 0.f ? tv.x * sv.x : 0.f);
        tile[r][cg * 4 + 1] = f2bf(tv.y > 0.f ? tv.y * sv.y : 0.f);
        tile[r][cg * 4 + 2] = f2bf(tv.z > 0.f ? tv.z * sv.z : 0.f);
        tile[r][cg * 4 + 3] = f2bf(tv.w > 0.f ? tv.w * sv.w : 0.f);
    }
    __syncthreads();
    #pragma unroll
    for (int i = 0; i < 4; ++i) {
        int idx = i * 256 + t;
        int nr = idx >> 4, kg = idx & 15;
        uint32_t lo = tile[kg * 4 + 0][nr] | ((uint32_t)tile[kg * 4 + 1][nr] << 16);
        uint32_t hi = tile[kg * 4 + 2][nr] | ((uint32_t)tile[kg * 4 + 3][nr] << 16);
        *(uint2*)&wT[(size_t)(bn * 64 + nr) * DD + bk * 64 + kg * 4] = make_uint2(lo, hi);
    }
}

// ---------------- 256x256 2-phase GEMM, BK=32, 64 KiB LDS -> 2 blocks/CU.
// T3-minimal loop: stage(t+1) at top, one barrier per tile, vmcnt covered by MFMA.
// C = relu(A . Bt^T).
// A_FP32: A fp32 (x) reg-staged (cvt_pk -> swizzled ds_write), stores bf16 (Y1).
// else  : A bf16 (Y1) via global_load_lds, stores fp32 (out).
template<bool A_FP32>
__global__ __launch_bounds__(512, 2) void gemm_2p(
        const void* __restrict__ Ap,
        const unsigned short* __restrict__ Bt,   // [1024 n][1024 k] bf16
        void* __restrict__ Cp) {
    __shared__ unsigned short sA[2][256 * 32];   // 16 KiB x2
    __shared__ unsigned short sB[2][256 * 32];   // 16 KiB x2  (64 KiB total)

    const int tid = threadIdx.x;
    const int lane = tid & 63, wid = tid >> 6;   // 8 waves
    const int wm = wid >> 2, wn = wid & 3;       // 2M x 4N
    const int fr = lane & 15, fq = lane >> 4;

    // T1: XCD-chunked bn-minor swizzle (512 blocks = 128 bm x 4 bn)
    const int s = blockIdx.x;
    const int L = (s & 7) * 64 + (s >> 3);
    const int bm = L >> 2, bn = L & 3;

    // staging: linear LDS dest; pre-swizzled global col-group (slot ^ (row>>1)&3)
    const int srow = wid * 16 + (lane >> 2);            // row within 128-row half
    const int scg  = (lane & 3) ^ ((srow >> 1) & 3);    // half-invariant (128 = 0 mod 4 after >>1&3)
    const unsigned short* bsrc = Bt + (size_t)(bn * 256 + srow) * DD + scg * 8;
    auto stageB = [&](int p, int u) {
        #pragma unroll
        for (int j = 0; j < 2; ++j)
            gload_lds16(bsrc + (size_t)j * 128 * DD + u * 32,
                        &sB[p][(j * 128 + wid * 16) * 32]);
    };

    const unsigned short* ahsrc = nullptr;
    const float* afsrc = nullptr;
    if constexpr (A_FP32) {
        afsrc = (const float*)Ap + (size_t)(bm * 256 + (tid >> 1)) * DD + (tid & 1) * 16;
    } else {
        ahsrc = (const unsigned short*)Ap + (size_t)(bm * 256 + srow) * DD + scg * 8;
    }
    auto stageA = [&](int p, int u) {   // bf16 path
        #pragma unroll
        for (int j = 0; j < 2; ++j)
            gload_lds16(ahsrc + (size_t)j * 128 * DD + u * 32,
                        &sA[p][(j * 128 + wid * 16) * 32]);
    };
    auto ldA = [&](f32x4 (&R)[4], int u) {   // fp32 path: 16 floats/thread
        #pragma unroll
        for (int j = 0; j < 4; ++j)
            R[j] = *(const f32x4*)(afsrc + u * 32 + j * 4);
    };
    auto wrA = [&](int p, f32x4 (&R)[4]) {
        const int row = tid >> 1;
        const int g = (row >> 1) & 3;
        const int s0 = (tid & 1) * 2;
        char* base = (char*)&sA[p][0] + row * 64;
        *(ushort8*)(base + (((s0 + 0) ^ g) << 4)) = cvt8pk(R[0], R[1]);
        *(ushort8*)(base + (((s0 + 1) ^ g) << 4)) = cvt8pk(R[2], R[3]);
    };

    const f32x4 vz = {0.f, 0.f, 0.f, 0.f};
    f32x4 acc[8][4];
    #pragma unroll
    for (int i = 0; i < 8; ++i)
        #pragma unroll
        for (int j = 0; j < 4; ++j) acc[i][j] = vz;

    // -------- prologue: tile 0 into buf 0 --------
    if constexpr (A_FP32) {
        f32x4 R0[4];
        ldA(R0, 0);
        stageB(0, 0);
        wrA(0, R0);              // compiler waits the reg loads
        LGKM0();
    } else {
        stageA(0, 0);
        stageB(0, 0);
    }
    VMC0();
    SBAR();

    // -------- main loop: 2 tiles per iteration, static buffer ids --------
    #pragma unroll 1
    for (int t2 = 0; t2 < NTK; t2 += 2) {
        #pragma unroll
        for (int h = 0; h < 2; ++h) {
            const int cur = h, nx = h ^ 1;
            const int t = t2 + h;
            f32x4 R[4];
            const bool pf = (t + 1 < NTK);
            // ---- stage tile t+1 into nx (issued first; overlaps reads+MFMA) ----
            if (pf) {
                if constexpr (A_FP32) { ldA(R, t + 1); stageB(nx, t + 1); }
                else                  { stageA(nx, t + 1); stageB(nx, t + 1); }
            }
            // ---- frag reads from cur (swizzled, ~2 lanes/bank) ----
            short8 av[8], bv[4];
            #pragma unroll
            for (int mi = 0; mi < 8; ++mi) {
                int row = wm * 128 + mi * 16 + fr;
                av[mi] = *(const short8*)((const char*)&sA[cur][0]
                            + row * 64 + (((fq ^ ((row >> 1) & 3))) << 4));
            }
            #pragma unroll
            for (int ni = 0; ni < 4; ++ni) {
                int row = wn * 64 + ni * 16 + fr;
                bv[ni] = *(const short8*)((const char*)&sB[cur][0]
                            + row * 64 + (((fq ^ ((row >> 1) & 3))) << 4));
            }
            LGKM0();
            SFENCE();            // rule #18: keep MFMA below the wait
            __builtin_amdgcn_s_setprio(1);
            #pragma unroll
            for (int mi = 0; mi < 8; ++mi)
                #pragma unroll
                for (int ni = 0; ni < 4; ++ni)
                    acc[mi][ni] = __builtin_amdgcn_mfma_f32_16x16x32_bf16(
                        av[mi], bv[ni], acc[mi][ni], 0, 0, 0);
            __builtin_amdgcn_s_setprio(0);
            SFENCE();            // keep wrA/vmcnt below the MFMA burst
            if constexpr (A_FP32) {
                if (pf) { wrA(nx, R); LGKM0(); }
            }
            VMC0();              // stage(t+1) done (latency covered by MFMA)
            SBAR();              // single barrier: nx staged + cur reads closed
        }
    }

    // -------- epilogue: ReLU + store --------
    const int orow0 = bm * 256 + wm * 128 + fq * 4;
    const int ocol0 = bn * 256 + wn * 64 + fr;
    #pragma unroll
    for (int mi = 0; mi < 8; ++mi)
        #pragma unroll
        for (int ni = 0; ni < 4; ++ni)
            #pragma unroll
            for (int r = 0; r < 4; ++r) {
                float v = fmaxf(acc[mi][ni][r], 0.f);
                size_t off = (size_t)(orow0 + mi * 16 + r) * DD + (ocol0 + ni * 16);
                if (A_FP32) ((unsigned short*)Cp)[off] = f2bf(v);
                else        ((float*)Cp)[off] = v;
            }
}

// ---------------- fallback (tiny workspace): fused fp32 VALU path
__global__ __launch_bounds__(256) void fallback_fused(
        const float* __restrict__ x,
        const float* __restrict__ th1, const float* __restrict__ sg1,
        const float* __restrict__ th2, const float* __restrict__ sg2,
        float* __restrict__ out) {
    __shared__ float xr[8][DD];
    __shared__ float y1[8][DD];
    const int rb = blockIdx.x * 8;
    const int t = threadIdx.x;
    for (int r = 0; r < 8; ++r)
        for (int i = t; i < DD; i += 256)
            xr[r][i] = x[(size_t)(rb + r) * DD + i];
    __syncthreads();
    for (int jo = 0; jo < 4; ++jo) {
        const int j = jo * 256 + t;
        float a[8] = {0, 0, 0, 0, 0, 0, 0, 0};
        for (int k = 0; k < DD; ++k) {
            float tv = th1[(size_t)k * DD + j];
            float w = tv > 0.f ? tv * sg1[(size_t)k * DD + j] : 0.f;
            #pragma unroll
            for (int r = 0; r < 8; ++r) a[r] += xr[r][k] * w;
        }
        #pragma unroll
        for (int r = 0; r < 8; ++r) y1[r][j] = fmaxf(a[r], 0.f);
    }
    __syncthreads();
    for (int jo = 0; jo < 4; ++jo) {
        const int j = jo * 256 + t;
        float a[8] = {0, 0, 0, 0, 0, 0, 0, 0};
        for (int k = 0; k < DD; ++k) {
            float tv = th2[(size_t)k * DD + j];
            float w = tv > 0.f ? tv * sg2[(size_t)k * DD + j] : 0.f;
            #pragma unroll
            for (int r = 0; r < 8; ++r) a[r] += y1[r][k] * w;
        }
        #pragma unroll
        for (int r = 0; r < 8; ++r) out[(size_t)(rb + r) * DD + j] = fmaxf(a[r], 0.f);
    }
}

extern "C" void kernel_launch(void* const* d_in, const int* in_sizes, int n_in,
                              void* d_out, int out_size, void* d_ws, size_t ws_size,
                              hipStream_t stream) {
    const float* x   = (const float*)d_in[0];
    const float* th1 = (const float*)d_in[1];
    const float* sg1 = (const float*)d_in[2];
    const float* th2 = (const float*)d_in[3];
    const float* sg2 = (const float*)d_in[4];
    float* out = (float*)d_out;

    const size_t need = ((size_t)2 * 1024 * 1024 + (size_t)MROWS * 1024) * 2;  // wT1+wT2+Y1 bf16
    if (ws_size >= need) {
        unsigned short* wT1 = (unsigned short*)d_ws;
        unsigned short* wT2 = wT1 + 1024 * 1024;
        unsigned short* Y1  = wT2 + 1024 * 1024;
        build_wT_kernel<<<dim3(16, 16, 2), 256, 0, stream>>>(th1, sg1, th2, sg2, wT1, wT2);
        gemm_2p<true ><<<dim3((MROWS / 256) * 4), 512, 0, stream>>>(x,  wT1, Y1);
        gemm_2p<false><<<dim3((MROWS / 256) * 4), 512, 0, stream>>>(Y1, wT2, out);
    } else {
        fallback_fused<<<MROWS / 8, 256, 0, stream>>>(x, th1, sg1, th2, sg2, out);
    }
}